// Round 5
// baseline (278.500 us; speedup 1.0000x reference)
//
#include <hip/hip_runtime.h>
#include <stdint.h>

typedef unsigned short ushort_t;
typedef __bf16 bf16x8 __attribute__((ext_vector_type(8)));
typedef float  f32x4  __attribute__((ext_vector_type(4)));
typedef float  f32x16 __attribute__((ext_vector_type(16)));

#define DEV static __device__ __forceinline__

// fp32 -> bf16 round-to-nearest-even
DEV ushort_t f2bf(float f){
  union { float f; unsigned u; } x; x.f = f;
  unsigned u = x.u;
  return (ushort_t)((u + 0x7fffu + ((u >> 16) & 1u)) >> 16);
}

// Boustrophedon map for S=8192 (g=91): involution, maps permuted<->original.
DEV int hmap(int p){
  int r = p / 91;
  int c = p - r * 91;
  return (r & 1) ? (r * 91 + 90 - c) : p;
}

// A-row gather modes: 0 identity; 1 = Q permuted order; 2 = compacted dilated KV.
template<int GATHER>
DEV int arow_map(int r){
  if (GATHER == 0) return r;
  if (GATHER == 1){ int b = r >> 13, p = r & 8191; return b * 8192 + hmap(p); }
  int b = r >> 12, rem = r & 4095, seg = rem >> 6, j = rem & 63;
  return b * 8192 + hmap(seg * 128 + 2 * j);
}

// async global->LDS 16B per lane (LDS dest must be uniform base + lane*16)
DEV void async16(const void* g, void* l){
  __builtin_amdgcn_global_load_lds(
      (const __attribute__((address_space(1))) unsigned*)g,
      (__attribute__((address_space(3))) unsigned*)l, 16, 0, 0);
}

// ---------------- cast x (fp32 -> bf16), vectorized, grid-stride ----------------
__global__ void cast_kernel(const float* __restrict__ in, ushort_t* __restrict__ out, int n4){
  int stride = gridDim.x * blockDim.x;
  for (int i = blockIdx.x * blockDim.x + threadIdx.x; i < n4; i += stride){
    float4 v = ((const float4*)in)[i];
    ushort4 o;
    o.x = f2bf(v.x); o.y = f2bf(v.y); o.z = f2bf(v.z); o.w = f2bf(v.w);
    ((ushort4*)out)[i] = o;
  }
}

// ---------- transpose + cast: W [rows][cols] fp32 -> WT [cols][rows] bf16 ----------
__global__ void transpose_cast(const float* __restrict__ W, ushort_t* __restrict__ WT,
                               int rows, int cols){
  __shared__ ushort_t t[64 * 66];   // pad 66: conflict-free column reads
  int tid = threadIdx.x;
  int c0 = blockIdx.x * 64, r0 = blockIdx.y * 64;
  int cl = tid & 63, rb = tid >> 6;
  for (int i = 0; i < 16; ++i){
    int r = rb + i * 4;
    t[r * 66 + cl] = f2bf(W[(size_t)(r0 + r) * cols + c0 + cl]);
  }
  __syncthreads();
  int rr = tid & 63, cb = tid >> 6;
  for (int i = 0; i < 16; ++i){
    int cc = cb + i * 4;
    WT[(size_t)(c0 + cc) * rows + r0 + rr] = t[rr * 66 + cc];
  }
}

// ================= 256x256 GEMM, 32x32x16 MFMA, coalesced epilogue ===========
// C[M][N] = A[gather(M)][K] * BT[N][K]^T. BM=BN=256, BK=64, 512 thr (8 waves,
// 2Mx4N, wave tile 128x64). LDS: 4 objects As0/As1/Bs0/Bs1, 128 KiB, 1 blk/CU.
//
// R0-R4 post-mortem: K-loop schedule family exhausted (4 variants, all 45-48us,
// MfmaUtil ~27%). The counter that moved: WRITE_SIZE = 2x ideal for bf16 C
// (2B/lane scatter stores -> partial 128B lines -> RMW), and the store burst
// is an exposed tail (all 256 lockstep blocks finish together). Fixes:
//  * 32x32x16 MFMA (R0-validated layout): 32 instead of 64 MFMA issues/tile,
//    2065 vs 2483 matrix-pipe cyc/tile (m119), and fp32 C/D stores are
//    full-128B-line by construction (col = lane&31).
//  * bf16 epilogue: wave-private LDS re-tile (stride-65 fp32, 2-way-free
//    banks) -> ushort4 full-line stores. No barriers (wave-private, after the
//    loop's final barrier all LDS readers are drained).
// K-loop: R4's 2-barrier/tile schedule (best of the family): stage t+1 into
// other buffer, vmcnt(8) (waits tile-t's DMAs, issued one compute region ago;
// t+1's 8 stay in flight across the barrier), barrier, whole-tile compute
// (24 ds_read_b128 + 32 MFMA, compiler-interleaved), barrier.
//
// LDS swizzle: row of 64 bf16 = 8x16B chunks; LDS slot s holds global chunk
// s^(row&7) (pre-swizzled global source, linear DMA dest). Fragment reads use
// the same XOR -> 0 bank conflicts (verified R1/R3/R4).
// Block map: plain n-major (measured-low FETCH 24.6MB).

#define BARRIER() asm volatile("s_barrier" ::: "memory")
#define VMCNT8()  asm volatile("s_waitcnt vmcnt(8)" ::: "memory")
#define VMCNT0()  asm volatile("s_waitcnt vmcnt(0)" ::: "memory")

#define STAGE_A_TO(DST, T1)                                                    \
  {                                                                            \
    _Pragma("unroll") for (int i = 0; i < 4; ++i)                              \
      async16(&A[asrcR[i] + (size_t)(T1) * 64], &DST[i * 4096 + tid * 8]);     \
  }

#define STAGE_B_TO(DST, T1)                                                    \
  {                                                                            \
    _Pragma("unroll") for (int i = 0; i < 4; ++i)                              \
      async16(&BT[bsrcR[i] + (size_t)(T1) * 64], &DST[i * 4096 + tid * 8]);    \
  }

// whole-tile compute, single region: B panel (8 reads) to regs, then per
// (kk,mi) A-frag read feeding 2 MFMAs. 24 ds_read_b128 + 32 v_mfma_32x32x16.
#define COMPUTE(ABUF, BBUF)                                                    \
  {                                                                            \
    bf16x8 bv[2][4];                                                           \
    _Pragma("unroll") for (int ni = 0; ni < 2; ++ni)                           \
      _Pragma("unroll") for (int kk = 0; kk < 4; ++kk)                         \
        bv[ni][kk] = *(const bf16x8*)&BBUF[(wn * 64 + ni * 32 + l31) * 64 + axor[kk]]; \
    _Pragma("unroll") for (int kk = 0; kk < 4; ++kk)                           \
      _Pragma("unroll") for (int mi = 0; mi < 4; ++mi){                        \
        bf16x8 af = *(const bf16x8*)&ABUF[(wm * 128 + mi * 32 + l31) * 64 + axor[kk]]; \
        _Pragma("unroll") for (int ni = 0; ni < 2; ++ni)                       \
          acc[mi][ni] = __builtin_amdgcn_mfma_f32_32x32x16_bf16(               \
              af, bv[ni][kk], acc[mi][ni], 0, 0, 0);                           \
      }                                                                        \
  }

// one pipeline step: stage tile TSTAGE into NXT buffers, wait for CUR's DMAs
// (1 tile old), barrier, compute CUR, barrier.
#define TILE_STEP(CUR, NXT, TSTAGE)                                            \
  {                                                                            \
    if ((TSTAGE) < NT){                                                        \
      STAGE_A_TO(As##NXT, TSTAGE); STAGE_B_TO(Bs##NXT, TSTAGE);                \
      VMCNT8();                                                                \
    } else { VMCNT0(); }                                                       \
    BARRIER();                                                                 \
    COMPUTE(As##CUR, Bs##CUR);                                                 \
    BARRIER();                                                                 \
  }

template<int OUT_BF16, int GATHER>
__global__ __launch_bounds__(512, 2) void gemm_bt(const ushort_t* __restrict__ A,
                                                  const ushort_t* __restrict__ BT,
                                                  void* __restrict__ Cout,
                                                  int M, int N, int K){
  __shared__ __align__(16) ushort_t As0[16384];
  __shared__ __align__(16) ushort_t As1[16384];
  __shared__ __align__(16) ushort_t Bs0[16384];
  __shared__ __align__(16) ushort_t Bs1[16384];
  const int NT = K >> 6;                           // K-tiles (=16, even)
  int tid = threadIdx.x;
  int lane = tid & 63, w = tid >> 6;
  int l31 = lane & 31, lh = lane >> 5;
  int wm = w >> 2, wn = w & 3;

  // n-major block map (measured-low FETCH: B panel shared chip-wide, L3
  // absorbs A re-reads)
  int o = blockIdx.x;
  int mtc = M >> 8;
  int nt = o / mtc, mt = o - nt * mtc;
  int m0 = mt << 8, n0 = nt << 8;

  // staging: thread covers LDS rows i*64 + (tid>>3), slot tid&7; global chunk
  // g0 = slot ^ (row&7)  ((64*i)&7==0 so g0 is i-independent)
  int rbase = tid >> 3;
  int g0 = ((tid & 7) ^ (rbase & 7)) * 8;          // elems
  size_t asrcR[4], bsrcR[4];
  #pragma unroll
  for (int i = 0; i < 4; ++i){
    asrcR[i] = (size_t)arow_map<GATHER>(m0 + i * 64 + rbase) * K + g0;
    bsrcR[i] = (size_t)(n0 + i * 64 + rbase) * K + g0;
  }

  // fragment k-chunk offsets: chunk = (2kk+lh) ^ (row&7), row&7 == l31&7
  // (A rows wm*128+mi*32+l31, B rows wn*64+ni*32+l31; 32/64/128 = 0 mod 8)
  int axor[4];
  #pragma unroll
  for (int kk = 0; kk < 4; ++kk)
    axor[kk] = (((kk << 1) | lh) ^ (l31 & 7)) * 8;

  f32x16 acc[4][2];
  #pragma unroll
  for (int a = 0; a < 4; ++a)
    #pragma unroll
    for (int b = 0; b < 2; ++b)
      #pragma unroll
      for (int e = 0; e < 16; ++e) acc[a][b][e] = 0.f;

  // prologue: tile 0 into buffers 0 (cold-start latency exposed once)
  STAGE_A_TO(As0, 0);
  STAGE_B_TO(Bs0, 0);
  VMCNT0(); BARRIER();

  for (int t = 0; t < NT; t += 2){
    TILE_STEP(0, 1, t + 1);
    TILE_STEP(1, 0, t + 2);
  }

  // ---------------- epilogue ----------------
  // 32x32 C/D layout: col = lane&31, row = (reg&3) + 8*(reg>>2) + 4*(lane>>5).
  if (OUT_BF16){
    // bf16: 2B/lane direct stores would half-fill 128B lines (measured 2x
    // WRITE_SIZE). Re-tile per-wave through LDS (free after final barrier;
    // wave-private -> no barriers): fp32 [32][65] (2-way-free banks both
    // directions), read back b128, pack, ushort4 full-line stores.
    float* wbuf;
    if (w < 3)      wbuf = (float*)As0 + w * 2080;
    else if (w < 6) wbuf = (float*)As1 + (w - 3) * 2080;
    else            wbuf = (float*)Bs0 + (w - 6) * 2080;
    int r16 = lane >> 4, c16 = lane & 15;
    #pragma unroll
    for (int mi = 0; mi < 4; ++mi){
      #pragma unroll
      for (int ni = 0; ni < 2; ++ni)
        #pragma unroll
        for (int reg = 0; reg < 16; ++reg){
          int row = (reg & 3) + 8 * (reg >> 2) + 4 * lh;
          wbuf[row * 65 + ni * 32 + l31] = acc[mi][ni][reg];
        }
      #pragma unroll
      for (int rr = 0; rr < 8; ++rr){
        int row = rr * 4 + r16;
        float4 v = *(const float4*)&wbuf[row * 65 + c16 * 4];
        int grow = m0 + wm * 128 + mi * 32 + row;
        int gcol = n0 + wn * 64 + c16 * 4;
        ushort4 ob;
        ob.x = f2bf(v.x); ob.y = f2bf(v.y); ob.z = f2bf(v.z); ob.w = f2bf(v.w);
        *(ushort4*)&((ushort_t*)Cout)[(size_t)grow * N + gcol] = ob;
      }
    }
  } else {
    // fp32: direct stores are already full 128B lines (32 lanes x 4B per row).
    #pragma unroll
    for (int mi = 0; mi < 4; ++mi)
      #pragma unroll
      for (int ni = 0; ni < 2; ++ni)
        #pragma unroll
        for (int reg = 0; reg < 16; ++reg){
          int row = (reg & 3) + 8 * (reg >> 2) + 4 * lh;
          int grow = m0 + wm * 128 + mi * 32 + row;
          int gcol = n0 + wn * 64 + ni * 32 + l31;
          ((float*)Cout)[(size_t)grow * N + gcol] = acc[mi][ni][reg];
        }
  }
}

// ---------------- fused segment attention ----------------
// grid (nseg=64, H=16, B=2), block 256 (4 waves).
// Qb:  [B*8192][1024] bf16, rows already in PERMUTED order (gemm1a GATHER=1).
// KV:  [B*4096][2048] bf16, rows in compacted dilated order seg*64+j
//      (gemm1b GATHER=2); cols 0..1023 = K, 1024..2047 = V.
// Vt stores V transposed with a k-chunk XOR swizzle: plain stride-72 layout
// put all 8 chunk-lanes of the transpose-store in ONE bank (d-stride 144B,
// 144*8 % 128 == 0 -> 8-way conflict x8 elems). Swizzle: k-chunk ^= (d>>3)&7.
__global__ __launch_bounds__(256) void attn_kernel(const ushort_t* __restrict__ Qb,
                                                   const ushort_t* __restrict__ KV,
                                                   ushort_t* __restrict__ aout){
  __shared__ ushort_t Qs[128 * 72];   // reused as P, then as O (wave-private rows)
  __shared__ ushort_t Ks[64 * 72];
  __shared__ ushort_t Vt[64 * 72];    // V transposed: Vt[d][k], k-chunk swizzled
  int tid  = threadIdx.x;
  int lane = tid & 63, w = tid >> 6;
  int qd = lane >> 4, md = lane & 15;
  int seg = blockIdx.x, h = blockIdx.y, b = blockIdx.z;
  int p0 = seg * 128;

  // Q: 128 rows x 64 bf16 (8 chunks of 16B per row), contiguous rows
  for (int it = 0; it < 4; ++it){
    int q = it * 256 + tid;
    int r = q >> 3, ch = q & 7;
    uint4 d = *(const uint4*)&Qb[(size_t)(b * 8192 + p0 + r) * 1024 + h * 64 + ch * 8];
    *(uint4*)&Qs[r * 72 + ch * 8] = d;
  }
  // K: compacted rows seg*64 + r
  for (int it = 0; it < 2; ++it){
    int q = it * 256 + tid;
    int r = q >> 3, ch = q & 7;
    uint4 d = *(const uint4*)&KV[(size_t)(b * 4096 + seg * 64 + r) * 2048 + h * 64 + ch * 8];
    *(uint4*)&Ks[r * 72 + ch * 8] = d;
  }
  // V (cols 1024..2047), stored transposed with swizzled k-chunk:
  // element V[k=r][d=ch*8+e] -> Vt[d*72 + ((r>>3)^ch)*8 + (r&7)]
  for (int it = 0; it < 2; ++it){
    int q = it * 256 + tid;
    int r = q >> 3, ch = q & 7;
    union { uint4 v; ushort_t u[8]; } d;
    d.v = *(const uint4*)&KV[(size_t)(b * 4096 + seg * 64 + r) * 2048 + 1024 + h * 64 + ch * 8];
    int kslot = ((r >> 3) ^ ch) * 8 + (r & 7);
    for (int e = 0; e < 8; ++e) Vt[(ch * 8 + e) * 72 + kslot] = d.u[e];
  }
  __syncthreads();

  // scores: wave w owns q-rows [32w, 32w+32): 2 row-tiles x 4 col-tiles
  f32x4 z = {0.f, 0.f, 0.f, 0.f};
  f32x4 sc[2][4];
  for (int mi = 0; mi < 2; ++mi) for (int ni = 0; ni < 4; ++ni) sc[mi][ni] = z;
  for (int kc = 0; kc < 2; ++kc){
    bf16x8 aq[2], bk[4];
    for (int mi = 0; mi < 2; ++mi)
      aq[mi] = *(const bf16x8*)&Qs[(w * 32 + mi * 16 + md) * 72 + kc * 32 + qd * 8];
    for (int ni = 0; ni < 4; ++ni)
      bk[ni] = *(const bf16x8*)&Ks[(ni * 16 + md) * 72 + kc * 32 + qd * 8];
    for (int mi = 0; mi < 2; ++mi)
      for (int ni = 0; ni < 4; ++ni)
        sc[mi][ni] = __builtin_amdgcn_mfma_f32_16x16x32_bf16(aq[mi], bk[ni], sc[mi][ni], 0, 0, 0);
  }

  // softmax over 64 keys; scale 1/sqrt(64)=0.125. Row r lives in 16 lanes
  // (same quad) x 4 col-tiles -> in-register + shfl_xor(1,2,4,8) reduction.
  const float scale = 0.125f;
  ushort_t* Ps = Qs;  // alias: wave only touches its own 32 rows
  for (int mi = 0; mi < 2; ++mi){
    for (int i = 0; i < 4; ++i){
      float mx = sc[mi][0][i];
      for (int ni = 1; ni < 4; ++ni) mx = fmaxf(mx, sc[mi][ni][i]);
      for (int d = 1; d < 16; d <<= 1) mx = fmaxf(mx, __shfl_xor(mx, d));
      float e[4], sum = 0.f;
      for (int ni = 0; ni < 4; ++ni){ e[ni] = __expf((sc[mi][ni][i] - mx) * scale); sum += e[ni]; }
      for (int d = 1; d < 16; d <<= 1) sum += __shfl_xor(sum, d);
      float inv = 1.0f / sum;
      int r = w * 32 + mi * 16 + qd * 4 + i;
      for (int ni = 0; ni < 4; ++ni)
        Ps[r * 72 + ni * 16 + md] = f2bf(e[ni] * inv);
    }
  }

  // O = P @ V : A = P (rows w*32..+31), B = Vt[d][k] (k-chunk swizzled)
  f32x4 oc[2][4];
  for (int mi = 0; mi < 2; ++mi) for (int ni = 0; ni < 4; ++ni) oc[mi][ni] = z;
  for (int kc = 0; kc < 2; ++kc){
    bf16x8 ap[2], bv[4];
    for (int mi = 0; mi < 2; ++mi)
      ap[mi] = *(const bf16x8*)&Ps[(w * 32 + mi * 16 + md) * 72 + kc * 32 + qd * 8];
    for (int ni = 0; ni < 4; ++ni){
      int dd = ni * 16 + md;
      int vchunk = ((kc * 4 + qd) ^ ((dd >> 3) & 7)) & 7;
      bv[ni] = *(const bf16x8*)&Vt[dd * 72 + vchunk * 8];
    }
    for (int mi = 0; mi < 2; ++mi)
      for (int ni = 0; ni < 4; ++ni)
        oc[mi][ni] = __builtin_amdgcn_mfma_f32_16x16x32_bf16(ap[mi], bv[ni], oc[mi][ni], 0, 0, 0);
  }

  // O back into wave-private LDS rows (overwrites this wave's P), then
  // one barrier and fully-coalesced 16B stores: row s=hmap(p0+r), 128B/row.
  for (int mi = 0; mi < 2; ++mi){
    for (int i = 0; i < 4; ++i){
      int rl = w * 32 + mi * 16 + qd * 4 + i;
      for (int ni = 0; ni < 4; ++ni)
        Ps[rl * 72 + ni * 16 + md] = f2bf(oc[mi][ni][i]);
    }
  }
  __syncthreads();
  for (int it = 0; it < 4; ++it){
    int q = it * 256 + tid;
    int r = q >> 3, ch = q & 7;
    int s = hmap(p0 + r);
    *(uint4*)&aout[(size_t)(b * 8192 + s) * 1024 + h * 64 + ch * 8] =
        *(const uint4*)&Qs[r * 72 + ch * 8];
  }
}

extern "C" void kernel_launch(void* const* d_in, const int* in_sizes, int n_in,
                              void* d_out, int out_size, void* d_ws, size_t ws_size,
                              hipStream_t stream){
  const float* x    = (const float*)d_in[0];   // [2,8192,1024]
  const float* Wqkv = (const float*)d_in[1];   // [1024,3072]
  const float* Wout = (const float*)d_in[2];   // [1024,1024]
  float* out = (float*)d_out;                  // [2,8192,1024]

  // ws layout (bytes): xb 32M | WqT 6M | WoT 2M | Qbuf 32M | KVbuf 32M | aout 32M = 136 MB
  char* ws = (char*)d_ws;
  ushort_t* xb    = (ushort_t*)(ws);
  ushort_t* WqT   = (ushort_t*)(ws + 33554432);
  ushort_t* WoT   = (ushort_t*)(ws + 39845888);
  ushort_t* Qbuf  = (ushort_t*)(ws + 41943040);
  ushort_t* KVbuf = (ushort_t*)(ws + 75497472);
  ushort_t* aoutb = (ushort_t*)(ws + 109051904);

  cast_kernel<<<2048, 256, 0, stream>>>(x, xb, (16384 * 1024) / 4);
  transpose_cast<<<dim3(48, 16), 256, 0, stream>>>(Wqkv, WqT, 1024, 3072);
  transpose_cast<<<dim3(16, 16), 256, 0, stream>>>(Wout, WoT, 1024, 1024);
  // Q projection: grid = (16384/256)*(1024/256) = 256
  gemm_bt<1, 1><<<dim3(256), dim3(512), 0, stream>>>(xb, WqT, Qbuf, 16384, 1024, 1024);
  // K,V projection: (8192/256)*(2048/256) = 256
  gemm_bt<1, 2><<<dim3(256), dim3(512), 0, stream>>>(xb, WqT + (size_t)1024 * 1024, KVbuf, 8192, 2048, 1024);
  attn_kernel<<<dim3(64, 16, 2), 256, 0, stream>>>(Qbuf, KVbuf, aoutb);
  // output projection
  gemm_bt<0, 0><<<dim3(256), dim3(512), 0, stream>>>(aoutb, WoT, out, 16384, 1024, 1024);
}

// Round 6
// 267.260 us; speedup vs baseline: 1.0421x; 1.0421x over previous
//
#include <hip/hip_runtime.h>
#include <stdint.h>

typedef unsigned short ushort_t;
typedef __bf16 bf16x8 __attribute__((ext_vector_type(8)));
typedef float  f32x4  __attribute__((ext_vector_type(4)));

#define DEV static __device__ __forceinline__

// fp32 -> bf16 round-to-nearest-even
DEV ushort_t f2bf(float f){
  union { float f; unsigned u; } x; x.f = f;
  unsigned u = x.u;
  return (ushort_t)((u + 0x7fffu + ((u >> 16) & 1u)) >> 16);
}

// Boustrophedon map for S=8192 (g=91): involution, maps permuted<->original.
DEV int hmap(int p){
  int r = p / 91;
  int c = p - r * 91;
  return (r & 1) ? (r * 91 + 90 - c) : p;
}

// A-row gather (runtime): 0 identity; 1 = Q permuted order; 2 = compacted dilated KV.
DEV int arow_rt(int r, int gather){
  if (gather == 0) return r;
  if (gather == 1){ int b = r >> 13, p = r & 8191; return b * 8192 + hmap(p); }
  int b = r >> 12, rem = r & 4095, seg = rem >> 6, j = rem & 63;
  return b * 8192 + hmap(seg * 128 + 2 * j);
}

// async global->LDS 16B per lane (LDS dest must be uniform base + lane*16)
DEV void async16(const void* g, void* l){
  __builtin_amdgcn_global_load_lds(
      (const __attribute__((address_space(1))) unsigned*)g,
      (__attribute__((address_space(3))) unsigned*)l, 16, 0, 0);
}

// ---------------- fused prep: cast x + transpose both weights ----------------
// blocks 0..2047: cast x (fp32->bf16, grid-stride over float4)
// blocks 2048..2815: transpose Wqkv [1024][3072] -> WqT [3072][1024]
// blocks 2816..3071: transpose Wout [1024][1024] -> WoT [1024][1024]
__global__ __launch_bounds__(256) void prep_kernel(const float* __restrict__ x,
                                                   const float* __restrict__ Wqkv,
                                                   const float* __restrict__ Wout,
                                                   ushort_t* __restrict__ xb,
                                                   ushort_t* __restrict__ WqT,
                                                   ushort_t* __restrict__ WoT){
  __shared__ ushort_t t[64 * 66];   // pad 66: conflict-free column reads
  int id = blockIdx.x, tid = threadIdx.x;
  if (id < 2048){
    const int n4 = (16384 * 1024) / 4;
    int stride = 2048 * 256;
    for (int i = id * 256 + tid; i < n4; i += stride){
      float4 v = ((const float4*)x)[i];
      ushort4 o;
      o.x = f2bf(v.x); o.y = f2bf(v.y); o.z = f2bf(v.z); o.w = f2bf(v.w);
      ((ushort4*)xb)[i] = o;
    }
    return;
  }
  const float* W; ushort_t* WT; int rows, cols, bx, by;
  if (id < 2816){ int q = id - 2048; W = Wqkv; WT = WqT; rows = 1024; cols = 3072; bx = q % 48; by = q / 48; }
  else          { int q = id - 2816; W = Wout; WT = WoT; rows = 1024; cols = 1024; bx = q % 16; by = q / 16; }
  int c0 = bx * 64, r0 = by * 64;
  int cl = tid & 63, rb = tid >> 6;
  for (int i = 0; i < 16; ++i){
    int r = rb + i * 4;
    t[r * 66 + cl] = f2bf(W[(size_t)(r0 + r) * cols + c0 + cl]);
  }
  __syncthreads();
  int rr = tid & 63, cb = tid >> 6;
  for (int i = 0; i < 16; ++i){
    int cc = cb + i * 4;
    WT[(size_t)(c0 + cc) * rows + r0 + rr] = t[rr * 66 + cc];
  }
}

// ================= 256x256 GEMM body (R4-frozen K-loop) =================
// C[M][N] = A[gather(M)][K] * BT[N][K]^T. BM=BN=256, BK=64, 512 thr (8 waves,
// 2Mx4N, wave tile 128x64). LDS: 4 objects As0/As1/Bs0/Bs1 (kernel-scope,
// passed in), 128 KiB, 1 blk/CU.
// K-loop = R4's family-optimum (6 schedules tried, all 44.5-48.5us):
//   STAGE(t+1 -> other buf); vmcnt(8) (waits tile-t's DMAs, issued one
//   compute region ago; t+1's 8 stay in flight); barrier; whole-tile COMPUTE
//   (24 ds_read_b128 + 64 mfma_16x16x32, compiler-interleaved); barrier.
// 16x16 fragment path is bank-conflict-free with the chunk^(row&7) swizzle
// (R4 measured 0; 32x32 is 4-way -> reverted, R5 lesson).
// bf16 epilogue: per-wave LDS re-tile (16x65 fp32) -> ushort4 full-128B-line
// stores (R5 verified the retile halves WRITE_SIZE; kept for tail-overlap in
// the fused kernel). fp32 epilogue: direct stores.

#define BARRIER() asm volatile("s_barrier" ::: "memory")
#define VMCNT8()  asm volatile("s_waitcnt vmcnt(8)" ::: "memory")
#define VMCNT0()  asm volatile("s_waitcnt vmcnt(0)" ::: "memory")

#define STAGE_A_TO(DST, T1)                                                    \
  {                                                                            \
    _Pragma("unroll") for (int i = 0; i < 4; ++i)                              \
      async16(&A[asrcR[i] + (size_t)(T1) * 64], &DST[i * 4096 + tid * 8]);     \
  }

#define STAGE_B_TO(DST, T1)                                                    \
  {                                                                            \
    _Pragma("unroll") for (int i = 0; i < 4; ++i)                              \
      async16(&BT[bsrcR[i] + (size_t)(T1) * 64], &DST[i * 4096 + tid * 8]);    \
  }

#define COMPUTE(ABUF, BBUF)                                                    \
  {                                                                            \
    bf16x8 bv[4][2];                                                           \
    _Pragma("unroll") for (int ni = 0; ni < 4; ++ni)                           \
      _Pragma("unroll") for (int kk = 0; kk < 2; ++kk)                         \
        bv[ni][kk] = *(const bf16x8*)&BBUF[(wn * 64 + ni * 16 + md) * 64 + axor[kk]]; \
    _Pragma("unroll") for (int kk = 0; kk < 2; ++kk)                           \
      _Pragma("unroll") for (int mi = 0; mi < 8; ++mi){                        \
        bf16x8 af = *(const bf16x8*)&ABUF[(wm * 128 + mi * 16 + md) * 64 + axor[kk]]; \
        _Pragma("unroll") for (int ni = 0; ni < 4; ++ni)                       \
          acc[mi][ni] = __builtin_amdgcn_mfma_f32_16x16x32_bf16(               \
              af, bv[ni][kk], acc[mi][ni], 0, 0, 0);                           \
      }                                                                        \
  }

#define TILE_STEP(CUR, NXT, TSTAGE)                                            \
  {                                                                            \
    if ((TSTAGE) < NT){                                                        \
      STAGE_A_TO(As##NXT, TSTAGE); STAGE_B_TO(Bs##NXT, TSTAGE);                \
      VMCNT8();                                                                \
    } else { VMCNT0(); }                                                       \
    BARRIER();                                                                 \
    COMPUTE(As##CUR, Bs##CUR);                                                 \
    BARRIER();                                                                 \
  }

template<int OUT_BF16>
DEV void gemm_body(const ushort_t* __restrict__ A, const ushort_t* __restrict__ BT,
                   void* __restrict__ Cout, int N, int K, int gather, int m0, int n0,
                   ushort_t* As0, ushort_t* As1, ushort_t* Bs0, ushort_t* Bs1){
  const int NT = K >> 6;                           // K-tiles (=16, even)
  int tid = threadIdx.x;
  int lane = tid & 63, w = tid >> 6;
  int md = lane & 15, qd = lane >> 4;
  int wm = w >> 2, wn = w & 3;

  // staging: thread covers LDS rows i*64 + (tid>>3), slot tid&7; global chunk
  // g0 = slot ^ (row&7)  ((64*i)&7==0 so g0 is i-independent)
  int rbase = tid >> 3;
  int g0 = ((tid & 7) ^ (rbase & 7)) * 8;          // elems
  size_t asrcR[4], bsrcR[4];
  #pragma unroll
  for (int i = 0; i < 4; ++i){
    asrcR[i] = (size_t)arow_rt(m0 + i * 64 + rbase, gather) * K + g0;
    bsrcR[i] = (size_t)(n0 + i * 64 + rbase) * K + g0;
  }

  // fragment offsets: frag row = (multiple of 8) + md -> row&7 == md&7
  int axor[2] = { (qd ^ (md & 7)) * 8, ((4 + qd) ^ (md & 7)) * 8 };

  f32x4 acc[8][4];
  #pragma unroll
  for (int a = 0; a < 8; ++a)
    #pragma unroll
    for (int b = 0; b < 4; ++b)
      #pragma unroll
      for (int e = 0; e < 4; ++e) acc[a][b][e] = 0.f;

  // prologue: tile 0 into buffers 0 (cold-start latency exposed once)
  STAGE_A_TO(As0, 0);
  STAGE_B_TO(Bs0, 0);
  VMCNT0(); BARRIER();

  for (int t = 0; t < NT; t += 2){
    TILE_STEP(0, 1, t + 1);
    TILE_STEP(1, 0, t + 2);
  }

  // epilogue: 16x16 C/D layout col=lane&15, row=(lane>>4)*4+reg
  if (OUT_BF16){
    // per-wave LDS re-tile (free after final barrier, wave-private -> no
    // barrier): 16x65 fp32 (65: 2-way-free banks), then ushort4 stores,
    // 16 lanes x 8B = full 128B line per output row.
    float* wbuf = (w < 4) ? ((float*)As0 + w * 1040) : ((float*)As1 + (w - 4) * 1040);
    int r16 = lane >> 4, c16 = lane & 15;
    #pragma unroll
    for (int mi = 0; mi < 8; ++mi){
      #pragma unroll
      for (int ni = 0; ni < 4; ++ni)
        #pragma unroll
        for (int reg = 0; reg < 4; ++reg)
          wbuf[(qd * 4 + reg) * 65 + ni * 16 + md] = acc[mi][ni][reg];
      // same-wave ds_write -> ds_read order is preserved by the LDS unit
      #pragma unroll
      for (int rr = 0; rr < 4; ++rr){
        int row = rr * 4 + r16;
        float4 v = *(const float4*)&wbuf[row * 65 + c16 * 4];
        int grow = m0 + wm * 128 + mi * 16 + row;
        int gcol = n0 + wn * 64 + c16 * 4;
        ushort4 ob;
        ob.x = f2bf(v.x); ob.y = f2bf(v.y); ob.z = f2bf(v.z); ob.w = f2bf(v.w);
        *(ushort4*)&((ushort_t*)Cout)[(size_t)grow * N + gcol] = ob;
      }
    }
  } else {
    #pragma unroll
    for (int mi = 0; mi < 8; ++mi)
      #pragma unroll
      for (int ni = 0; ni < 4; ++ni){
        f32x4 v = acc[mi][ni];
        #pragma unroll
        for (int reg = 0; reg < 4; ++reg){
          int grow = m0 + wm * 128 + mi * 16 + qd * 4 + reg;
          int gcol = n0 + wn * 64 + ni * 16 + md;
          ((float*)Cout)[(size_t)grow * N + gcol] = v[reg];
        }
      }
  }
}

// -------- fused Q + KV projection: 512 blocks, block-routed --------
// blocks 0..255:   Qbuf  = xb[gather=1] @ WqT          (M=16384, N=1024)
// blocks 256..511: KVbuf = xb[gather=2] @ WqT[K|V part] (M=8192, N=2048)
// Independent problems; KV blocks backfill CUs as Q blocks retire -> the two
// lockstep tails + one kernel boundary become overlap.
__global__ __launch_bounds__(512, 2) void gemm_qkv(const ushort_t* __restrict__ xb,
                                                   const ushort_t* __restrict__ WqT,
                                                   ushort_t* __restrict__ Qbuf,
                                                   ushort_t* __restrict__ KVbuf){
  __shared__ __align__(16) ushort_t As0[16384];
  __shared__ __align__(16) ushort_t As1[16384];
  __shared__ __align__(16) ushort_t Bs0[16384];
  __shared__ __align__(16) ushort_t Bs1[16384];
  int id = blockIdx.x;
  const ushort_t* BT; ushort_t* C; int N, gather, m0, n0;
  if (id < 256){
    int o = id;                       // n-major, mtc=64
    m0 = (o & 63) << 8; n0 = (o >> 6) << 8;
    BT = WqT; C = Qbuf; N = 1024; gather = 1;
  } else {
    int o = id - 256;                 // n-major, mtc=32
    m0 = (o & 31) << 8; n0 = (o >> 5) << 8;
    BT = WqT + (size_t)1024 * 1024; C = KVbuf; N = 2048; gather = 2;
  }
  gemm_body<1>(xb, BT, C, N, 1024, gather, m0, n0, As0, As1, Bs0, Bs1);
}

// -------- output projection: fp32 out, identity gather --------
__global__ __launch_bounds__(512, 2) void gemm_out(const ushort_t* __restrict__ aoutb,
                                                   const ushort_t* __restrict__ WoT,
                                                   float* __restrict__ out){
  __shared__ __align__(16) ushort_t As0[16384];
  __shared__ __align__(16) ushort_t As1[16384];
  __shared__ __align__(16) ushort_t Bs0[16384];
  __shared__ __align__(16) ushort_t Bs1[16384];
  int o = blockIdx.x;                 // n-major, mtc=64
  int m0 = (o & 63) << 8, n0 = (o >> 6) << 8;
  gemm_body<0>(aoutb, WoT, out, 1024, 1024, 0, m0, n0, As0, As1, Bs0, Bs1);
}

// ---------------- fused segment attention ----------------
// grid (nseg=64, H=16, B=2), block 256 (4 waves).
// Qb:  [B*8192][1024] bf16, rows already in PERMUTED order (gemm1a gather=1).
// KV:  [B*4096][2048] bf16, rows in compacted dilated order seg*64+j
//      (gemm1b gather=2); cols 0..1023 = K, 1024..2047 = V.
// Vt stores V transposed with a k-chunk XOR swizzle: plain stride-72 layout
// put all 8 chunk-lanes of the transpose-store in ONE bank (d-stride 144B,
// 144*8 % 128 == 0 -> 8-way conflict x8 elems). Swizzle: k-chunk ^= (d>>3)&7.
__global__ __launch_bounds__(256) void attn_kernel(const ushort_t* __restrict__ Qb,
                                                   const ushort_t* __restrict__ KV,
                                                   ushort_t* __restrict__ aout){
  __shared__ ushort_t Qs[128 * 72];   // reused as P, then as O (wave-private rows)
  __shared__ ushort_t Ks[64 * 72];
  __shared__ ushort_t Vt[64 * 72];    // V transposed: Vt[d][k], k-chunk swizzled
  int tid  = threadIdx.x;
  int lane = tid & 63, w = tid >> 6;
  int qd = lane >> 4, md = lane & 15;
  int seg = blockIdx.x, h = blockIdx.y, b = blockIdx.z;
  int p0 = seg * 128;

  // Q: 128 rows x 64 bf16 (8 chunks of 16B per row), contiguous rows
  for (int it = 0; it < 4; ++it){
    int q = it * 256 + tid;
    int r = q >> 3, ch = q & 7;
    uint4 d = *(const uint4*)&Qb[(size_t)(b * 8192 + p0 + r) * 1024 + h * 64 + ch * 8];
    *(uint4*)&Qs[r * 72 + ch * 8] = d;
  }
  // K: compacted rows seg*64 + r
  for (int it = 0; it < 2; ++it){
    int q = it * 256 + tid;
    int r = q >> 3, ch = q & 7;
    uint4 d = *(const uint4*)&KV[(size_t)(b * 4096 + seg * 64 + r) * 2048 + h * 64 + ch * 8];
    *(uint4*)&Ks[r * 72 + ch * 8] = d;
  }
  // V (cols 1024..2047), stored transposed with swizzled k-chunk:
  // element V[k=r][d=ch*8+e] -> Vt[d*72 + ((r>>3)^ch)*8 + (r&7)]
  for (int it = 0; it < 2; ++it){
    int q = it * 256 + tid;
    int r = q >> 3, ch = q & 7;
    union { uint4 v; ushort_t u[8]; } d;
    d.v = *(const uint4*)&KV[(size_t)(b * 4096 + seg * 64 + r) * 2048 + 1024 + h * 64 + ch * 8];
    int kslot = ((r >> 3) ^ ch) * 8 + (r & 7);
    for (int e = 0; e < 8; ++e) Vt[(ch * 8 + e) * 72 + kslot] = d.u[e];
  }
  __syncthreads();

  // scores: wave w owns q-rows [32w, 32w+32): 2 row-tiles x 4 col-tiles
  f32x4 z = {0.f, 0.f, 0.f, 0.f};
  f32x4 sc[2][4];
  for (int mi = 0; mi < 2; ++mi) for (int ni = 0; ni < 4; ++ni) sc[mi][ni] = z;
  for (int kc = 0; kc < 2; ++kc){
    bf16x8 aq[2], bk[4];
    for (int mi = 0; mi < 2; ++mi)
      aq[mi] = *(const bf16x8*)&Qs[(w * 32 + mi * 16 + md) * 72 + kc * 32 + qd * 8];
    for (int ni = 0; ni < 4; ++ni)
      bk[ni] = *(const bf16x8*)&Ks[(ni * 16 + md) * 72 + kc * 32 + qd * 8];
    for (int mi = 0; mi < 2; ++mi)
      for (int ni = 0; ni < 4; ++ni)
        sc[mi][ni] = __builtin_amdgcn_mfma_f32_16x16x32_bf16(aq[mi], bk[ni], sc[mi][ni], 0, 0, 0);
  }

  // softmax over 64 keys; scale 1/sqrt(64)=0.125. Row r lives in 16 lanes
  // (same quad) x 4 col-tiles -> in-register + shfl_xor(1,2,4,8) reduction.
  const float scale = 0.125f;
  ushort_t* Ps = Qs;  // alias: wave only touches its own 32 rows
  for (int mi = 0; mi < 2; ++mi){
    for (int i = 0; i < 4; ++i){
      float mx = sc[mi][0][i];
      for (int ni = 1; ni < 4; ++ni) mx = fmaxf(mx, sc[mi][ni][i]);
      for (int d = 1; d < 16; d <<= 1) mx = fmaxf(mx, __shfl_xor(mx, d));
      float e[4], sum = 0.f;
      for (int ni = 0; ni < 4; ++ni){ e[ni] = __expf((sc[mi][ni][i] - mx) * scale); sum += e[ni]; }
      for (int d = 1; d < 16; d <<= 1) sum += __shfl_xor(sum, d);
      float inv = 1.0f / sum;
      int r = w * 32 + mi * 16 + qd * 4 + i;
      for (int ni = 0; ni < 4; ++ni)
        Ps[r * 72 + ni * 16 + md] = f2bf(e[ni] * inv);
    }
  }

  // O = P @ V : A = P (rows w*32..+31), B = Vt[d][k] (k-chunk swizzled)
  f32x4 oc[2][4];
  for (int mi = 0; mi < 2; ++mi) for (int ni = 0; ni < 4; ++ni) oc[mi][ni] = z;
  for (int kc = 0; kc < 2; ++kc){
    bf16x8 ap[2], bv[4];
    for (int mi = 0; mi < 2; ++mi)
      ap[mi] = *(const bf16x8*)&Ps[(w * 32 + mi * 16 + md) * 72 + kc * 32 + qd * 8];
    for (int ni = 0; ni < 4; ++ni){
      int dd = ni * 16 + md;
      int vchunk = ((kc * 4 + qd) ^ ((dd >> 3) & 7)) & 7;
      bv[ni] = *(const bf16x8*)&Vt[dd * 72 + vchunk * 8];
    }
    for (int mi = 0; mi < 2; ++mi)
      for (int ni = 0; ni < 4; ++ni)
        oc[mi][ni] = __builtin_amdgcn_mfma_f32_16x16x32_bf16(ap[mi], bv[ni], oc[mi][ni], 0, 0, 0);
  }

  // O back into wave-private LDS rows (overwrites this wave's P), then
  // one barrier and fully-coalesced 16B stores: row s=hmap(p0+r), 128B/row.
  for (int mi = 0; mi < 2; ++mi){
    for (int i = 0; i < 4; ++i){
      int rl = w * 32 + mi * 16 + qd * 4 + i;
      for (int ni = 0; ni < 4; ++ni)
        Ps[rl * 72 + ni * 16 + md] = f2bf(oc[mi][ni][i]);
    }
  }
  __syncthreads();
  for (int it = 0; it < 4; ++it){
    int q = it * 256 + tid;
    int r = q >> 3, ch = q & 7;
    int s = hmap(p0 + r);
    *(uint4*)&aout[(size_t)(b * 8192 + s) * 1024 + h * 64 + ch * 8] =
        *(const uint4*)&Qs[r * 72 + ch * 8];
  }
}

extern "C" void kernel_launch(void* const* d_in, const int* in_sizes, int n_in,
                              void* d_out, int out_size, void* d_ws, size_t ws_size,
                              hipStream_t stream){
  const float* x    = (const float*)d_in[0];   // [2,8192,1024]
  const float* Wqkv = (const float*)d_in[1];   // [1024,3072]
  const float* Wout = (const float*)d_in[2];   // [1024,1024]
  float* out = (float*)d_out;                  // [2,8192,1024]

  // ws layout (bytes): xb 32M | WqT 6M | WoT 2M | Qbuf 32M | KVbuf 32M | aout 32M = 136 MB
  char* ws = (char*)d_ws;
  ushort_t* xb    = (ushort_t*)(ws);
  ushort_t* WqT   = (ushort_t*)(ws + 33554432);
  ushort_t* WoT   = (ushort_t*)(ws + 39845888);
  ushort_t* Qbuf  = (ushort_t*)(ws + 41943040);
  ushort_t* KVbuf = (ushort_t*)(ws + 75497472);
  ushort_t* aoutb = (ushort_t*)(ws + 109051904);

  // 4 launches (was 7): prep (cast + 2 transposes), fused QKV GEMM, attn, out GEMM
  prep_kernel<<<3072, 256, 0, stream>>>(x, Wqkv, Wout, xb, WqT, WoT);
  gemm_qkv<<<512, 512, 0, stream>>>(xb, WqT, Qbuf, KVbuf);
  attn_kernel<<<dim3(64, 16, 2), 256, 0, stream>>>(Qbuf, KVbuf, aoutb);
  gemm_out<<<256, 512, 0, stream>>>(aoutb, WoT, out);
}